// Round 17
// baseline (115.171 us; speedup 1.0000x reference)
//
#include <hip/hip_runtime.h>
#include <hip/hip_bf16.h>
#include <math.h>

// ---------------- problem constants ----------------
#define D_MODEL   1024
#define K_TOT     32
#define N_DECAY   28
#define M_DIM     8
#define KS        4
#define H_DIM     32
#define DIM_K     1024
#define DIM_MEM   1056
#define DIM_Q     2048
#define TOTAL_DIM 3104
#define NPAD_IN   3328          // 13 * 256
#define B_SZ      2
#define L_SEQ     2048
#define BL_TOT    4096

#define KG_CNT    4             // k-groups of 8
#define NCHUNK    64
#define CHUNK_L   32            // L_SEQ / NCHUNK

typedef __attribute__((ext_vector_type(8))) __bf16 bf16x8;
typedef __attribute__((ext_vector_type(4))) __bf16 bf16x4;
typedef __attribute__((ext_vector_type(4))) float  f32x4;

__device__ __forceinline__ void gload_lds16(const void* g, void* l) {
    __builtin_amdgcn_global_load_lds(
        (const __attribute__((address_space(1))) void*)g,
        (__attribute__((address_space(3))) void*)l, 16, 0, 0);
}

// ================= GEMM1: 128x256 tile, single-buffered (R11 best) ==========
__global__ __launch_bounds__(512, 4) void gemm_big(const __bf16* __restrict__ A,
                                                   const __bf16* __restrict__ Bt,
                                                   __bf16* __restrict__ Cmem,
                                                   __bf16* __restrict__ Cq,
                                                   int Kdim, int gx) {
    __shared__ __bf16 As[128 * 64];          // 16 KiB
    __shared__ __bf16 Bs[256 * 64];          // 32 KiB

    const int tid  = threadIdx.x;
    const int w    = tid >> 6;               // 0..7
    const int lane = tid & 63;
    const int l15  = lane & 15;
    const int l16  = lane >> 4;
    const int wm   = w >> 2;                 // 0..1 (M halves, 64 rows)
    const int wn   = w & 3;                  // 0..3 (N quarters, 64 cols)

    const int nwg = gridDim.x;
    int lin = blockIdx.x;
    lin = (lin & 7) * (nwg >> 3) + (lin >> 3);
    const int bx = lin % gx, by = lin / gx;
    const int r0 = by * 128, c0 = bx * 256;

    const int srl   = lane >> 3;             // 0..7
    const int sslot = lane & 7;

    f32x4 acc[4][4] = {};
    const int NT = Kdim / 64;                // 16

    for (int t = 0; t < NT; ++t) {
        const int k0 = t * 64;
#pragma unroll
        for (int j = 0; j < 2; j++) {
            const int r_  = j * 64 + w * 8 + srl;
            const int so_ = sslot ^ (r_ & 7);
            gload_lds16(A + (size_t)(r0 + r_) * Kdim + k0 + so_ * 8,
                        &As[(j * 64 + w * 8) * 64]);
        }
#pragma unroll
        for (int j = 0; j < 4; j++) {
            const int r_  = j * 64 + w * 8 + srl;
            const int so_ = sslot ^ (r_ & 7);
            gload_lds16(Bt + (size_t)(c0 + r_) * Kdim + k0 + so_ * 8,
                        &Bs[(j * 64 + w * 8) * 64]);
        }
        __syncthreads();

#pragma unroll
        for (int kk = 0; kk < 2; kk++) {
            bf16x8 a[4], b[4];
#pragma unroll
            for (int ni = 0; ni < 4; ni++) {
                const int col  = wn * 64 + ni * 16 + l15;
                const int slot = (kk * 4 + l16) ^ (col & 7);
                b[ni] = *(const bf16x8*)&Bs[col * 64 + slot * 8];
            }
#pragma unroll
            for (int mi = 0; mi < 4; mi++) {
                const int row  = wm * 64 + mi * 16 + l15;
                const int slot = (kk * 4 + l16) ^ (row & 7);
                a[mi] = *(const bf16x8*)&As[row * 64 + slot * 8];
            }
            __builtin_amdgcn_s_setprio(1);
#pragma unroll
            for (int mi = 0; mi < 4; mi++)
#pragma unroll
                for (int ni = 0; ni < 4; ni++)
                    acc[mi][ni] = __builtin_amdgcn_mfma_f32_16x16x32_bf16(
                        a[mi], b[ni], acc[mi][ni], 0, 0, 0);
            __builtin_amdgcn_s_setprio(0);
        }
        __syncthreads();
    }

#pragma unroll
    for (int mi = 0; mi < 4; mi++) {
#pragma unroll
        for (int ni = 0; ni < 4; ni++) {
            const int col = c0 + wn * 64 + ni * 16 + l15;
            const int row = r0 + wm * 64 + mi * 16 + l16 * 4;
            if (col < DIM_MEM) {
#pragma unroll
                for (int q = 0; q < 4; q++)
                    Cmem[(size_t)(row + q) * DIM_MEM + col] = (__bf16)acc[mi][ni][q];
            } else if (col < TOTAL_DIM) {
#pragma unroll
                for (int q = 0; q < 4; q++)
                    Cq[(size_t)(row + q) * DIM_Q + (col - DIM_MEM)] =
                        (__bf16)acc[mi][ni][q];
            }
        }
    }
}

// ================= GEMM2: 128^2 tile, 8 waves, dbuf + counted vmcnt =========
__global__ __launch_bounds__(512, 2) void gemm_mid(const __bf16* __restrict__ A,
                                                   const __bf16* __restrict__ Bt,
                                                   float* __restrict__ C,
                                                   int Ndim, int Kdim, int gx) {
    __shared__ __bf16 lds[2][2][128 * 64];   // 64 KiB

    const int tid  = threadIdx.x;
    const int w    = tid >> 6;
    const int lane = tid & 63;
    const int l15  = lane & 15;
    const int l16  = lane >> 4;
    const int wm   = w >> 1;
    const int wn   = w & 1;

    const int nwg = gridDim.x;
    int lin = blockIdx.x;
    lin = (lin & 7) * (nwg >> 3) + (lin >> 3);
    const int bx = lin % gx, by = lin / gx;
    const int r0 = by * 128, c0 = bx * 128;

    const int srl   = lane >> 3;
    const int sslot = lane & 7;

    f32x4 acc[2][4] = {};
    const int NT = Kdim / 64;

#define STG4(T, BUF)                                                           \
    _Pragma("unroll") for (int j = 0; j < 2; j++) {                            \
        const int r_  = j * 64 + w * 8 + srl;                                  \
        const int so_ = sslot ^ (r_ & 7);                                      \
        gload_lds16(A + (size_t)(r0 + r_) * Kdim + (T) * 64 + so_ * 8,         \
                    &lds[BUF][0][(j * 64 + w * 8) * 64]);                      \
        gload_lds16(Bt + (size_t)(c0 + r_) * Kdim + (T) * 64 + so_ * 8,        \
                    &lds[BUF][1][(j * 64 + w * 8) * 64]);                      \
    }

    STG4(0, 0);
    STG4(1, 1);
    __builtin_amdgcn_sched_barrier(0);
    asm volatile("s_waitcnt vmcnt(4)" ::: "memory");
    __builtin_amdgcn_s_barrier();
    __builtin_amdgcn_sched_barrier(0);

    for (int t = 0; t < NT; ++t) {
        const int cur = t & 1;
        const __bf16* As_ = &lds[cur][0][0];
        const __bf16* Bs_ = &lds[cur][1][0];
        const bool pf = (t + 2 < NT);

        bf16x8 b[4][2], a[2][2];
#pragma unroll
        for (int ni = 0; ni < 4; ni++)
#pragma unroll
            for (int kk = 0; kk < 2; kk++) {
                const int col  = wn * 64 + ni * 16 + l15;
                const int slot = (kk * 4 + l16) ^ (col & 7);
                b[ni][kk] = *(const bf16x8*)&Bs_[col * 64 + slot * 8];
            }
#pragma unroll
        for (int mi = 0; mi < 2; mi++)
#pragma unroll
            for (int kk = 0; kk < 2; kk++) {
                const int row  = wm * 32 + mi * 16 + l15;
                const int slot = (kk * 4 + l16) ^ (row & 7);
                a[mi][kk] = *(const bf16x8*)&As_[row * 64 + slot * 8];
            }
        asm volatile("s_waitcnt lgkmcnt(0)" ::: "memory");
        __builtin_amdgcn_sched_barrier(0);
        __builtin_amdgcn_s_setprio(1);
#pragma unroll
        for (int kk = 0; kk < 2; kk++)
#pragma unroll
            for (int mi = 0; mi < 2; mi++)
#pragma unroll
                for (int ni = 0; ni < 4; ni++)
                    acc[mi][ni] = __builtin_amdgcn_mfma_f32_16x16x32_bf16(
                        a[mi][kk], b[ni][kk], acc[mi][ni], 0, 0, 0);
        __builtin_amdgcn_s_setprio(0);
        __builtin_amdgcn_sched_barrier(0);
        __builtin_amdgcn_s_barrier();
        if (pf) STG4(t + 2, cur);
        __builtin_amdgcn_sched_barrier(0);
        if (pf) asm volatile("s_waitcnt vmcnt(4)" ::: "memory");
        else    asm volatile("s_waitcnt vmcnt(0)" ::: "memory");
        __builtin_amdgcn_s_barrier();
        __builtin_amdgcn_sched_barrier(0);
    }
#undef STG4

#pragma unroll
    for (int mi = 0; mi < 2; mi++) {
#pragma unroll
        for (int ni = 0; ni < 4; ni++) {
            const int col = c0 + wn * 64 + ni * 16 + l15;
            const int row = r0 + wm * 32 + mi * 16 + l16 * 4;
#pragma unroll
            for (int q = 0; q < 4; q++)
                C[(size_t)(row + q) * Ndim + col] = acc[mi][ni][q];
        }
    }
}

// ============== merged prep: cast x + transpose W_in + transpose W_out ======
#define CAST_BLOCKS 4096
#define TIN_BX      (NPAD_IN / 32)
#define TIN_BLOCKS  (TIN_BX * (D_MODEL / 32))
#define TOUT_BX     (D_MODEL / 32)
#define TOUT_BLOCKS (TOUT_BX * (D_MODEL / 32))

__global__ __launch_bounds__(256) void prep_all(const float* __restrict__ x,
                                                const float* __restrict__ W_in,
                                                const float* __restrict__ W_out,
                                                __bf16* __restrict__ x_b,
                                                __bf16* __restrict__ W_in_T,
                                                __bf16* __restrict__ W_out_T) {
    __shared__ float tile[32][33];
    const int bid = blockIdx.x;
    const int t = threadIdx.x;

    if (bid < CAST_BLOCKS) {
        const int i = bid * 256 + t;
        const float4 v = ((const float4*)x)[i];
        bf16x4 o;
        o.x = (__bf16)v.x; o.y = (__bf16)v.y; o.z = (__bf16)v.z; o.w = (__bf16)v.w;
        ((bf16x4*)x_b)[i] = o;
        return;
    }

    const bool is_in = (bid < CAST_BLOCKS + TIN_BLOCKS);
    const int lb = is_in ? (bid - CAST_BLOCKS) : (bid - CAST_BLOCKS - TIN_BLOCKS);
    const int bx_ = is_in ? TIN_BX : TOUT_BX;
    const int Ndim = is_in ? TOTAL_DIM : D_MODEL;
    const float* W = is_in ? W_in : W_out;
    __bf16* Wt = is_in ? W_in_T : W_out_T;

    const int n0 = (lb % bx_) * 32, k0 = (lb / bx_) * 32;
    const int tx = t & 31, ty = t >> 5;
#pragma unroll
    for (int i = 0; i < 32; i += 8) {
        float v = 0.f;
        if (n0 + tx < Ndim) v = W[(size_t)(k0 + ty + i) * Ndim + n0 + tx];
        tile[ty + i][tx] = v;
    }
    __syncthreads();
#pragma unroll
    for (int i = 0; i < 32; i += 8) {
        const int n = n0 + ty + i;
        Wt[(size_t)n * D_MODEL + k0 + tx] = (__bf16)tile[tx][ty + i];
    }
}

// ======== conv context ======================================================
struct ConvCtx {
    float ck0, ck1, ck2, ck3;
    float gk0, gk1, gk2, gk3;
    float ssc, c0_, c1_;
    int   ch, gc;
};

__device__ __forceinline__ ConvCtx make_ctx(const float* __restrict__ conv_k,
                                            const float* __restrict__ score_scale,
                                            const float* __restrict__ decay_slopes,
                                            const float* __restrict__ anchor_slopes,
                                            int k, int h) {
    ConvCtx cx;
    cx.ch = k * H_DIM + h;
    cx.gc = DIM_K + k;
    cx.ck0 = conv_k[0 * DIM_MEM + cx.ch];
    cx.ck1 = conv_k[1 * DIM_MEM + cx.ch];
    cx.ck2 = conv_k[2 * DIM_MEM + cx.ch];
    cx.ck3 = conv_k[3 * DIM_MEM + cx.ch];
    cx.gk0 = conv_k[0 * DIM_MEM + cx.gc];
    cx.gk1 = conv_k[1 * DIM_MEM + cx.gc];
    cx.gk2 = conv_k[2 * DIM_MEM + cx.gc];
    cx.gk3 = conv_k[3 * DIM_MEM + cx.gc];
    cx.ssc = score_scale[k];
    if (k < N_DECAY) {
        const float sd = log1pf(__expf(decay_slopes[k]));
        cx.c0_ = -sd * (float)(L_SEQ - 1); cx.c1_ = sd;
    } else {
        const float sa = log1pf(__expf(anchor_slopes[k - N_DECAY]));
        cx.c0_ = 0.f; cx.c1_ = -sa;
    }
    return cx;
}

// ---------------- phase 1: fused conv + per-chunk totals ---------------------
// blockIdx in [0, B*KG*NCHUNK): c = idx & 63, bkg = idx >> 6.
__global__ __launch_bounds__(256) void chunk_sums(const __bf16* __restrict__ z_mem,
                                                  const float* __restrict__ conv_k,
                                                  const float* __restrict__ score_scale,
                                                  const float* __restrict__ decay_slopes,
                                                  const float* __restrict__ anchor_slopes,
                                                  const float* __restrict__ theta,
                                                  __bf16* __restrict__ k_val,
                                                  float* __restrict__ p_w,
                                                  float* __restrict__ csum,
                                                  float* __restrict__ cden) {
    const int idx = blockIdx.x;
    const int c = idx & (NCHUNK - 1);
    const int bkg = idx >> 6;
    const int kg = bkg & (KG_CNT - 1);
    const int b = bkg / KG_CNT;
    const int t = threadIdx.x;
    const int kl = t >> 5;
    const int h = t & 31;
    const int k = kg * 8 + kl;
    const int bk = b * K_TOT + k;

    const ConvCtx cx = make_ctx(conv_k, score_scale, decay_slopes, anchor_slopes, k, h);
    const float A4 = theta[4];

    const int l0 = c * CHUNK_L;
    const __bf16* zb = z_mem + (size_t)b * L_SEQ * DIM_MEM;

    float z1 = (l0 >= 3) ? (float)zb[(size_t)(l0 - 3) * DIM_MEM + cx.ch] : 0.f;
    float z2 = (l0 >= 2) ? (float)zb[(size_t)(l0 - 2) * DIM_MEM + cx.ch] : 0.f;
    float z3 = (l0 >= 1) ? (float)zb[(size_t)(l0 - 1) * DIM_MEM + cx.ch] : 0.f;
    float g1 = (l0 >= 3) ? (float)zb[(size_t)(l0 - 3) * DIM_MEM + cx.gc] : 0.f;
    float g2 = (l0 >= 2) ? (float)zb[(size_t)(l0 - 2) * DIM_MEM + cx.gc] : 0.f;
    float g3 = (l0 >= 1) ? (float)zb[(size_t)(l0 - 1) * DIM_MEM + cx.gc] : 0.f;

    float r[4] = {}, im[4] = {};
    float den = 0.f;
#pragma unroll 4
    for (int i = 0; i < CHUNK_L; i++) {
        const int l = l0 + i;
        const size_t bl = (size_t)b * L_SEQ + l;
        const float z0 = (float)zb[(size_t)l * DIM_MEM + cx.ch];
        const float g0 = (float)zb[(size_t)l * DIM_MEM + cx.gc];
        const float kvf = fmaf(cx.ck0, z1, fmaf(cx.ck1, z2, fmaf(cx.ck2, z3, cx.ck3 * z0)));
        const float gvv = fmaf(cx.gk0, g1, fmaf(cx.gk1, g2, fmaf(cx.gk2, g3, cx.gk3 * g0)));
        z1 = z2; z2 = z3; z3 = z0;
        g1 = g2; g2 = g3; g3 = g0;

        const __bf16 kvb = (__bf16)kvf;
        const float kv = (float)kvb;            // bf16-rounded (matches scan_out)
        const float lp = fminf(fmaxf(cx.ssc * gvv, -20.f), 20.f);
        const float p  = __expf(lp + cx.c0_ + cx.c1_ * (float)l);

        k_val[bl * DIM_K + cx.ch] = kvb;
        if (h == 0) p_w[bl * K_TOT + k] = p;

        float cc = __cosf(kv * A4), ss = __sinf(kv * A4);
        const float cd = fmaf(cc, cc, -(ss * ss));
        const float sd = 2.f * cc * ss;
        r[0]  = fmaf(p, cc, r[0]);
        im[0] = fmaf(p, ss, im[0]);
#pragma unroll
        for (int j = 1; j < 4; j++) {
            const float c2 = fmaf(cc, cd, -(ss * sd));
            ss = fmaf(ss, cd, cc * sd);
            cc = c2;
            r[j]  = fmaf(p, cc, r[j]);
            im[j] = fmaf(p, ss, im[j]);
        }
        den += p;
    }

    float* base = &csum[((size_t)bk * NCHUNK + c) * 256 + h * 8];
    *(f32x4*)base       = f32x4{ r[0], im[0], r[1], im[1] };
    *(f32x4*)(base + 4) = f32x4{ r[2], im[2], r[3], im[3] };
    if (h == 0) cden[bk * NCHUNK + c] = den;
}

// ---------------- phase 2: exclusive prefix (4x parallel, 256 blk x 64 thr) --
// blockIdx = bk*4 + qq ; thread t handles csum position qq*64 + t over 64 chunks
__global__ __launch_bounds__(64) void chunk_prefix(float* __restrict__ csum,
                                                   float* __restrict__ cden) {
    const int bk = blockIdx.x >> 2;
    const int qq = blockIdx.x & 3;
    const int t = threadIdx.x;          // 0..63
    const int pos = qq * 64 + t;

    if (qq == 0) {
        const float a0 = cden[bk * NCHUNK + t];
        float v0 = a0;
#pragma unroll
        for (int d = 1; d < 64; d <<= 1) {
            const float u0 = __shfl_up(v0, d);
            if (t >= d) v0 += u0;
        }
        cden[bk * NCHUNK + t] = v0 - a0;
    }

    float run = 0.f;
#pragma unroll
    for (int g = 0; g < NCHUNK / 8; g++) {
        float vv[8];
#pragma unroll
        for (int j = 0; j < 8; j++)
            vv[j] = csum[((size_t)bk * NCHUNK + g * 8 + j) * 256 + pos];
#pragma unroll
        for (int j = 0; j < 8; j++) {
            const float x = vv[j];
            vv[j] = run;
            run += x;
        }
#pragma unroll
        for (int j = 0; j < 8; j++)
            csum[((size_t)bk * NCHUNK + g * 8 + j) * 256 + pos] = vv[j];
    }
}

// ---------------- phase 3: replay + epilogue (direct q, unroll 4) ------------
__global__ __launch_bounds__(256) void scan_out(const __bf16* __restrict__ q_b,
                                                const __bf16* __restrict__ k_val,
                                                const float* __restrict__ p_w,
                                                const float* __restrict__ theta,
                                                const float* __restrict__ csum,
                                                const float* __restrict__ cden,
                                                const float* __restrict__ W_re,
                                                const float* __restrict__ W_im,
                                                const float* __restrict__ norm_scale,
                                                __bf16* __restrict__ y) {
    const int idx = blockIdx.x;
    const int c = idx & (NCHUNK - 1);
    const int bkg = idx >> 6;
    const int kg = bkg & (KG_CNT - 1);
    const int b = bkg / KG_CNT;
    const int t = threadIdx.x;
    const int kl = t >> 5;
    const int h = t & 31;
    const int k = kg * 8 + kl;
    const int bk = b * K_TOT + k;

    const float A4 = theta[4];

    float r[4], im[4];
    {
        const float* base = &csum[((size_t)bk * NCHUNK + c) * 256 + h * 8];
        const f32x4 v0 = *(const f32x4*)base;
        const f32x4 v1 = *(const f32x4*)(base + 4);
        r[0] = v0.x; im[0] = v0.y; r[1] = v0.z; im[1] = v0.w;
        r[2] = v1.x; im[2] = v1.y; r[3] = v1.z; im[3] = v1.w;
    }
    float den = cden[bk * NCHUNK + c];

    const float wsc_re = norm_scale[h] * W_re[h * H_DIM + h];
    const float wsc_im = norm_scale[H_DIM + h] * W_im[h * H_DIM + h];

    const int l0 = c * CHUNK_L;
#pragma unroll 4
    for (int i = 0; i < CHUNK_L; i++) {
        const size_t bl = (size_t)b * L_SEQ + (l0 + i);
        const float p  = p_w[bl * K_TOT + k];
        const float kv = (float)k_val[bl * DIM_K + k * H_DIM + h];

        const __bf16* qp = &q_b[bl * DIM_Q + (size_t)(kg * H_DIM + h) * 16];
        const bf16x8 q0 = *(const bf16x8*)qp;
        const bf16x8 q1 = *(const bf16x8*)(qp + 8);

        float cc = __cosf(kv * A4), ss = __sinf(kv * A4);
        const float cd = fmaf(cc, cc, -(ss * ss));
        const float sd = 2.f * cc * ss;

        float ore = 0.f, oim = 0.f;
#pragma unroll
        for (int j = 0; j < 4; j++) {
            if (j > 0) {
                const float c2 = fmaf(cc, cd, -(ss * sd));
                ss = fmaf(ss, cd, cc * sd);
                cc = c2;
            }
            r[j]  = fmaf(p, cc, r[j]);
            im[j] = fmaf(p, ss, im[j]);
            const float qrm = (float)q1[2 * j];
            const float qim = (float)q1[2 * j + 1];
            const float qrj = (float)q0[2 * (3 - j)];
            const float qij = (float)q0[2 * (3 - j) + 1];
            ore = fmaf(r[j],  qrm + qrj, fmaf(im[j], qim - qij, ore));
            oim = fmaf(im[j], qrm - qrj, fmaf(-r[j], qim + qij, oim));
        }
        den += p;
        const float inv = __builtin_amdgcn_rcpf(fmaxf(den, 1e-4f));

        const float v = (ore * wsc_re + oim * wsc_im) * inv;
        const float yv = v * __builtin_amdgcn_rcpf(1.0f + __expf(-v));
        y[bl * DIM_K + k * H_DIM + h] = (__bf16)yv;
    }
}

// ---------------- launch ----------------
extern "C" void kernel_launch(void* const* d_in, const int* in_sizes, int n_in,
                              void* d_out, int out_size, void* d_ws, size_t ws_size,
                              hipStream_t stream) {
    const float* x            = (const float*)d_in[0];
    const float* W_in         = (const float*)d_in[1];
    const float* conv_k       = (const float*)d_in[2];
    const float* theta        = (const float*)d_in[3];
    const float* decay_slopes = (const float*)d_in[4];
    const float* anchor_slopes= (const float*)d_in[5];
    const float* score_scale  = (const float*)d_in[6];
    const float* W_re         = (const float*)d_in[7];
    const float* W_im         = (const float*)d_in[8];
    const float* norm_scale   = (const float*)d_in[9];
    const float* W_out        = (const float*)d_in[10];
    float* out = (float*)d_out;

    float* ws = (float*)d_ws;
    size_t off = 0;
    float* p_w    = ws + off; off += (size_t)BL_TOT * K_TOT;
    float* csum   = ws + off; off += (size_t)B_SZ * K_TOT * NCHUNK * 256;
    float* cden   = ws + off; off += (size_t)B_SZ * K_TOT * NCHUNK;
    __bf16* z_mem_b = (__bf16*)(ws + off); off += (size_t)BL_TOT * DIM_MEM / 2 + 8;
    __bf16* k_val   = (__bf16*)(ws + off); off += (size_t)BL_TOT * DIM_K / 2;
    __bf16* x_b     = (__bf16*)(ws + off); off += (size_t)BL_TOT * D_MODEL / 2;
    __bf16* W_in_T  = (__bf16*)(ws + off); off += (size_t)NPAD_IN * D_MODEL / 2;
    __bf16* W_out_T = (__bf16*)(ws + off); off += (size_t)D_MODEL * D_MODEL / 2;
    __bf16* y_b     = (__bf16*)(ws + off); off += (size_t)BL_TOT * DIM_K / 2;
    __bf16* q_b     = (__bf16*)(ws + off); off += (size_t)BL_TOT * DIM_Q / 2;

    // 0) merged prep
    prep_all<<<CAST_BLOCKS + TIN_BLOCKS + TOUT_BLOCKS, 256, 0, stream>>>(
        x, W_in, W_out, x_b, W_in_T, W_out_T);

    // 1) z = x @ W_in (128x256 single-buffered, row-major XCD mapping)
    gemm_big<<<(NPAD_IN / 256) * (BL_TOT / 128), 512, 0, stream>>>(
        x_b, W_in_T, z_mem_b, q_b, D_MODEL, NPAD_IN / 256);

    // 2) fused conv + per-chunk totals
    chunk_sums<<<B_SZ * KG_CNT * NCHUNK, 256, 0, stream>>>(
        z_mem_b, conv_k, score_scale, decay_slopes, anchor_slopes, theta,
        k_val, p_w, csum, cden);
    // 3) prefix (4x parallel) + replay
    chunk_prefix<<<B_SZ * K_TOT * 4, 64, 0, stream>>>(csum, cden);
    scan_out<<<B_SZ * KG_CNT * NCHUNK, 256, 0, stream>>>(q_b, k_val, p_w, theta, csum,
                                                         cden, W_re, W_im, norm_scale, y_b);
    // 4) out = y @ W_out (128^2, 8-wave pipelined)
    gemm_mid<<<(D_MODEL / 128) * (BL_TOT / 128), 512, 0, stream>>>(
        y_b, W_out_T, out, D_MODEL, D_MODEL, D_MODEL / 128);
}

// Round 18
// 103.095 us; speedup vs baseline: 1.1171x; 1.1171x over previous
//
#include <hip/hip_runtime.h>
#include <hip/hip_bf16.h>
#include <math.h>

// ---------------- problem constants ----------------
#define D_MODEL   1024
#define K_TOT     32
#define N_DECAY   28
#define M_DIM     8
#define KS        4
#define H_DIM     32
#define DIM_K     1024
#define DIM_MEM   1056
#define DIM_Q     2048
#define TOTAL_DIM 3104
#define NPAD_IN   3328          // 13 * 256
#define B_SZ      2
#define L_SEQ     2048
#define BL_TOT    4096

#define KG_CNT    4             // k-groups of 8
#define NCHUNK    128
#define CHUNK_L   16            // L_SEQ / NCHUNK

typedef __attribute__((ext_vector_type(8))) __bf16 bf16x8;
typedef __attribute__((ext_vector_type(4))) __bf16 bf16x4;
typedef __attribute__((ext_vector_type(4))) float  f32x4;

__device__ __forceinline__ void gload_lds16(const void* g, void* l) {
    __builtin_amdgcn_global_load_lds(
        (const __attribute__((address_space(1))) void*)g,
        (__attribute__((address_space(3))) void*)l, 16, 0, 0);
}

// ================= GEMM1: 128x256 tile, single-buffered (R11 best) ==========
__global__ __launch_bounds__(512, 4) void gemm_big(const __bf16* __restrict__ A,
                                                   const __bf16* __restrict__ Bt,
                                                   __bf16* __restrict__ Cmem,
                                                   __bf16* __restrict__ Cq,
                                                   int Kdim, int gx) {
    __shared__ __bf16 As[128 * 64];          // 16 KiB
    __shared__ __bf16 Bs[256 * 64];          // 32 KiB

    const int tid  = threadIdx.x;
    const int w    = tid >> 6;               // 0..7
    const int lane = tid & 63;
    const int l15  = lane & 15;
    const int l16  = lane >> 4;
    const int wm   = w >> 2;                 // 0..1 (M halves, 64 rows)
    const int wn   = w & 3;                  // 0..3 (N quarters, 64 cols)

    const int nwg = gridDim.x;
    int lin = blockIdx.x;
    lin = (lin & 7) * (nwg >> 3) + (lin >> 3);
    const int bx = lin % gx, by = lin / gx;
    const int r0 = by * 128, c0 = bx * 256;

    const int srl   = lane >> 3;             // 0..7
    const int sslot = lane & 7;

    f32x4 acc[4][4] = {};
    const int NT = Kdim / 64;                // 16

    for (int t = 0; t < NT; ++t) {
        const int k0 = t * 64;
#pragma unroll
        for (int j = 0; j < 2; j++) {
            const int r_  = j * 64 + w * 8 + srl;
            const int so_ = sslot ^ (r_ & 7);
            gload_lds16(A + (size_t)(r0 + r_) * Kdim + k0 + so_ * 8,
                        &As[(j * 64 + w * 8) * 64]);
        }
#pragma unroll
        for (int j = 0; j < 4; j++) {
            const int r_  = j * 64 + w * 8 + srl;
            const int so_ = sslot ^ (r_ & 7);
            gload_lds16(Bt + (size_t)(c0 + r_) * Kdim + k0 + so_ * 8,
                        &Bs[(j * 64 + w * 8) * 64]);
        }
        __syncthreads();

#pragma unroll
        for (int kk = 0; kk < 2; kk++) {
            bf16x8 a[4], b[4];
#pragma unroll
            for (int ni = 0; ni < 4; ni++) {
                const int col  = wn * 64 + ni * 16 + l15;
                const int slot = (kk * 4 + l16) ^ (col & 7);
                b[ni] = *(const bf16x8*)&Bs[col * 64 + slot * 8];
            }
#pragma unroll
            for (int mi = 0; mi < 4; mi++) {
                const int row  = wm * 64 + mi * 16 + l15;
                const int slot = (kk * 4 + l16) ^ (row & 7);
                a[mi] = *(const bf16x8*)&As[row * 64 + slot * 8];
            }
            __builtin_amdgcn_s_setprio(1);
#pragma unroll
            for (int mi = 0; mi < 4; mi++)
#pragma unroll
                for (int ni = 0; ni < 4; ni++)
                    acc[mi][ni] = __builtin_amdgcn_mfma_f32_16x16x32_bf16(
                        a[mi], b[ni], acc[mi][ni], 0, 0, 0);
            __builtin_amdgcn_s_setprio(0);
        }
        __syncthreads();
    }

#pragma unroll
    for (int mi = 0; mi < 4; mi++) {
#pragma unroll
        for (int ni = 0; ni < 4; ni++) {
            const int col = c0 + wn * 64 + ni * 16 + l15;
            const int row = r0 + wm * 64 + mi * 16 + l16 * 4;
            if (col < DIM_MEM) {
#pragma unroll
                for (int q = 0; q < 4; q++)
                    Cmem[(size_t)(row + q) * DIM_MEM + col] = (__bf16)acc[mi][ni][q];
            } else if (col < TOTAL_DIM) {
#pragma unroll
                for (int q = 0; q < 4; q++)
                    Cq[(size_t)(row + q) * DIM_Q + (col - DIM_MEM)] =
                        (__bf16)acc[mi][ni][q];
            }
        }
    }
}

// ================= GEMM2: 128^2 tile, 8 waves, dbuf + counted vmcnt =========
__global__ __launch_bounds__(512, 2) void gemm_mid(const __bf16* __restrict__ A,
                                                   const __bf16* __restrict__ Bt,
                                                   float* __restrict__ C,
                                                   int Ndim, int Kdim, int gx) {
    __shared__ __bf16 lds[2][2][128 * 64];   // 64 KiB

    const int tid  = threadIdx.x;
    const int w    = tid >> 6;
    const int lane = tid & 63;
    const int l15  = lane & 15;
    const int l16  = lane >> 4;
    const int wm   = w >> 1;
    const int wn   = w & 1;

    const int nwg = gridDim.x;
    int lin = blockIdx.x;
    lin = (lin & 7) * (nwg >> 3) + (lin >> 3);
    const int bx = lin % gx, by = lin / gx;
    const int r0 = by * 128, c0 = bx * 128;

    const int srl   = lane >> 3;
    const int sslot = lane & 7;

    f32x4 acc[2][4] = {};
    const int NT = Kdim / 64;

#define STG4(T, BUF)                                                           \
    _Pragma("unroll") for (int j = 0; j < 2; j++) {                            \
        const int r_  = j * 64 + w * 8 + srl;                                  \
        const int so_ = sslot ^ (r_ & 7);                                      \
        gload_lds16(A + (size_t)(r0 + r_) * Kdim + (T) * 64 + so_ * 8,         \
                    &lds[BUF][0][(j * 64 + w * 8) * 64]);                      \
        gload_lds16(Bt + (size_t)(c0 + r_) * Kdim + (T) * 64 + so_ * 8,        \
                    &lds[BUF][1][(j * 64 + w * 8) * 64]);                      \
    }

    STG4(0, 0);
    STG4(1, 1);
    __builtin_amdgcn_sched_barrier(0);
    asm volatile("s_waitcnt vmcnt(4)" ::: "memory");
    __builtin_amdgcn_s_barrier();
    __builtin_amdgcn_sched_barrier(0);

    for (int t = 0; t < NT; ++t) {
        const int cur = t & 1;
        const __bf16* As_ = &lds[cur][0][0];
        const __bf16* Bs_ = &lds[cur][1][0];
        const bool pf = (t + 2 < NT);

        bf16x8 b[4][2], a[2][2];
#pragma unroll
        for (int ni = 0; ni < 4; ni++)
#pragma unroll
            for (int kk = 0; kk < 2; kk++) {
                const int col  = wn * 64 + ni * 16 + l15;
                const int slot = (kk * 4 + l16) ^ (col & 7);
                b[ni][kk] = *(const bf16x8*)&Bs_[col * 64 + slot * 8];
            }
#pragma unroll
        for (int mi = 0; mi < 2; mi++)
#pragma unroll
            for (int kk = 0; kk < 2; kk++) {
                const int row  = wm * 32 + mi * 16 + l15;
                const int slot = (kk * 4 + l16) ^ (row & 7);
                a[mi][kk] = *(const bf16x8*)&As_[row * 64 + slot * 8];
            }
        asm volatile("s_waitcnt lgkmcnt(0)" ::: "memory");
        __builtin_amdgcn_sched_barrier(0);
        __builtin_amdgcn_s_setprio(1);
#pragma unroll
        for (int kk = 0; kk < 2; kk++)
#pragma unroll
            for (int mi = 0; mi < 2; mi++)
#pragma unroll
                for (int ni = 0; ni < 4; ni++)
                    acc[mi][ni] = __builtin_amdgcn_mfma_f32_16x16x32_bf16(
                        a[mi][kk], b[ni][kk], acc[mi][ni], 0, 0, 0);
        __builtin_amdgcn_s_setprio(0);
        __builtin_amdgcn_sched_barrier(0);
        __builtin_amdgcn_s_barrier();
        if (pf) STG4(t + 2, cur);
        __builtin_amdgcn_sched_barrier(0);
        if (pf) asm volatile("s_waitcnt vmcnt(4)" ::: "memory");
        else    asm volatile("s_waitcnt vmcnt(0)" ::: "memory");
        __builtin_amdgcn_s_barrier();
        __builtin_amdgcn_sched_barrier(0);
    }
#undef STG4

#pragma unroll
    for (int mi = 0; mi < 2; mi++) {
#pragma unroll
        for (int ni = 0; ni < 4; ni++) {
            const int col = c0 + wn * 64 + ni * 16 + l15;
            const int row = r0 + wm * 32 + mi * 16 + l16 * 4;
#pragma unroll
            for (int q = 0; q < 4; q++)
                C[(size_t)(row + q) * Ndim + col] = acc[mi][ni][q];
        }
    }
}

// ============== merged prep: cast x + transpose W_in + transpose W_out ======
#define CAST_BLOCKS 4096
#define TIN_BX      (NPAD_IN / 32)
#define TIN_BLOCKS  (TIN_BX * (D_MODEL / 32))
#define TOUT_BX     (D_MODEL / 32)
#define TOUT_BLOCKS (TOUT_BX * (D_MODEL / 32))

__global__ __launch_bounds__(256) void prep_all(const float* __restrict__ x,
                                                const float* __restrict__ W_in,
                                                const float* __restrict__ W_out,
                                                __bf16* __restrict__ x_b,
                                                __bf16* __restrict__ W_in_T,
                                                __bf16* __restrict__ W_out_T) {
    __shared__ float tile[32][33];
    const int bid = blockIdx.x;
    const int t = threadIdx.x;

    if (bid < CAST_BLOCKS) {
        const int i = bid * 256 + t;
        const float4 v = ((const float4*)x)[i];
        bf16x4 o;
        o.x = (__bf16)v.x; o.y = (__bf16)v.y; o.z = (__bf16)v.z; o.w = (__bf16)v.w;
        ((bf16x4*)x_b)[i] = o;
        return;
    }

    const bool is_in = (bid < CAST_BLOCKS + TIN_BLOCKS);
    const int lb = is_in ? (bid - CAST_BLOCKS) : (bid - CAST_BLOCKS - TIN_BLOCKS);
    const int bx_ = is_in ? TIN_BX : TOUT_BX;
    const int Ndim = is_in ? TOTAL_DIM : D_MODEL;
    const float* W = is_in ? W_in : W_out;
    __bf16* Wt = is_in ? W_in_T : W_out_T;

    const int n0 = (lb % bx_) * 32, k0 = (lb / bx_) * 32;
    const int tx = t & 31, ty = t >> 5;
#pragma unroll
    for (int i = 0; i < 32; i += 8) {
        float v = 0.f;
        if (n0 + tx < Ndim) v = W[(size_t)(k0 + ty + i) * Ndim + n0 + tx];
        tile[ty + i][tx] = v;
    }
    __syncthreads();
#pragma unroll
    for (int i = 0; i < 32; i += 8) {
        const int n = n0 + ty + i;
        Wt[(size_t)n * D_MODEL + k0 + tx] = (__bf16)tile[tx][ty + i];
    }
}

// ======== conv context ======================================================
struct ConvCtx {
    float ck0, ck1, ck2, ck3;
    float gk0, gk1, gk2, gk3;
    float ssc, c0_, c1_;
    int   ch, gc;
};

__device__ __forceinline__ ConvCtx make_ctx(const float* __restrict__ conv_k,
                                            const float* __restrict__ score_scale,
                                            const float* __restrict__ decay_slopes,
                                            const float* __restrict__ anchor_slopes,
                                            int k, int h) {
    ConvCtx cx;
    cx.ch = k * H_DIM + h;
    cx.gc = DIM_K + k;
    cx.ck0 = conv_k[0 * DIM_MEM + cx.ch];
    cx.ck1 = conv_k[1 * DIM_MEM + cx.ch];
    cx.ck2 = conv_k[2 * DIM_MEM + cx.ch];
    cx.ck3 = conv_k[3 * DIM_MEM + cx.ch];
    cx.gk0 = conv_k[0 * DIM_MEM + cx.gc];
    cx.gk1 = conv_k[1 * DIM_MEM + cx.gc];
    cx.gk2 = conv_k[2 * DIM_MEM + cx.gc];
    cx.gk3 = conv_k[3 * DIM_MEM + cx.gc];
    cx.ssc = score_scale[k];
    if (k < N_DECAY) {
        const float sd = log1pf(__expf(decay_slopes[k]));
        cx.c0_ = -sd * (float)(L_SEQ - 1); cx.c1_ = sd;
    } else {
        const float sa = log1pf(__expf(anchor_slopes[k - N_DECAY]));
        cx.c0_ = 0.f; cx.c1_ = -sa;
    }
    return cx;
}

// ---------------- phase 1: fused conv + per-chunk totals ---------------------
__global__ __launch_bounds__(256) void chunk_sums(const __bf16* __restrict__ z_mem,
                                                  const float* __restrict__ conv_k,
                                                  const float* __restrict__ score_scale,
                                                  const float* __restrict__ decay_slopes,
                                                  const float* __restrict__ anchor_slopes,
                                                  const float* __restrict__ theta,
                                                  __bf16* __restrict__ k_val,
                                                  float* __restrict__ p_w,
                                                  float* __restrict__ csum,
                                                  float* __restrict__ cden) {
    const int idx = blockIdx.x;
    const int c = idx & (NCHUNK - 1);
    const int bkg = idx >> 7;
    const int kg = bkg & (KG_CNT - 1);
    const int b = bkg / KG_CNT;
    const int t = threadIdx.x;
    const int kl = t >> 5;
    const int h = t & 31;
    const int k = kg * 8 + kl;
    const int bk = b * K_TOT + k;

    const ConvCtx cx = make_ctx(conv_k, score_scale, decay_slopes, anchor_slopes, k, h);
    const float A4 = theta[4];

    const int l0 = c * CHUNK_L;
    const __bf16* zb = z_mem + (size_t)b * L_SEQ * DIM_MEM;

    // load the whole chunk's z/g upfront (full prefetch window)
    float zv[CHUNK_L + 3], gv_[CHUNK_L + 3];
#pragma unroll
    for (int r = 0; r < 3; r++) {
        const int tl = l0 - 3 + r;
        zv[r]  = (tl >= 0) ? (float)zb[(size_t)tl * DIM_MEM + cx.ch] : 0.f;
        gv_[r] = (tl >= 0) ? (float)zb[(size_t)tl * DIM_MEM + cx.gc] : 0.f;
    }
#pragma unroll
    for (int i = 0; i < CHUNK_L; i++) {
        zv[3 + i]  = (float)zb[(size_t)(l0 + i) * DIM_MEM + cx.ch];
        gv_[3 + i] = (float)zb[(size_t)(l0 + i) * DIM_MEM + cx.gc];
    }

    float r[4] = {}, im[4] = {};
    float den = 0.f;
#pragma unroll
    for (int i = 0; i < CHUNK_L; i++) {
        const int l = l0 + i;
        const size_t bl = (size_t)b * L_SEQ + l;
        const float kvf = fmaf(cx.ck0, zv[i], fmaf(cx.ck1, zv[i + 1],
                          fmaf(cx.ck2, zv[i + 2], cx.ck3 * zv[i + 3])));
        const float gvv = fmaf(cx.gk0, gv_[i], fmaf(cx.gk1, gv_[i + 1],
                          fmaf(cx.gk2, gv_[i + 2], cx.gk3 * gv_[i + 3])));

        const __bf16 kvb = (__bf16)kvf;
        const float kv = (float)kvb;            // bf16-rounded (matches scan_out)
        const float lp = fminf(fmaxf(cx.ssc * gvv, -20.f), 20.f);
        const float p  = __expf(lp + cx.c0_ + cx.c1_ * (float)l);

        k_val[bl * DIM_K + cx.ch] = kvb;
        if (h == 0) p_w[bl * K_TOT + k] = p;

        float cc = __cosf(kv * A4), ss = __sinf(kv * A4);
        const float cd = fmaf(cc, cc, -(ss * ss));
        const float sd = 2.f * cc * ss;
        r[0]  = fmaf(p, cc, r[0]);
        im[0] = fmaf(p, ss, im[0]);
#pragma unroll
        for (int j = 1; j < 4; j++) {
            const float c2 = fmaf(cc, cd, -(ss * sd));
            ss = fmaf(ss, cd, cc * sd);
            cc = c2;
            r[j]  = fmaf(p, cc, r[j]);
            im[j] = fmaf(p, ss, im[j]);
        }
        den += p;
    }

    float* base = &csum[((size_t)bk * NCHUNK + c) * 256 + h * 8];
    *(f32x4*)base       = f32x4{ r[0], im[0], r[1], im[1] };
    *(f32x4*)(base + 4) = f32x4{ r[2], im[2], r[3], im[3] };
    if (h == 0) cden[bk * NCHUNK + c] = den;
}

// ---------------- phase 2: exclusive prefix (4x parallel, 256 blk x 64 thr) --
__global__ __launch_bounds__(64) void chunk_prefix(float* __restrict__ csum,
                                                   float* __restrict__ cden) {
    const int bk = blockIdx.x >> 2;
    const int qq = blockIdx.x & 3;
    const int t = threadIdx.x;          // 0..63
    const int pos = qq * 64 + t;

    if (qq == 0) {
        const float a0 = cden[bk * NCHUNK + t];
        const float a1 = cden[bk * NCHUNK + 64 + t];
        float v0 = a0, v1 = a1;
#pragma unroll
        for (int d = 1; d < 64; d <<= 1) {
            const float u0 = __shfl_up(v0, d);
            const float u1 = __shfl_up(v1, d);
            if (t >= d) { v0 += u0; v1 += u1; }
        }
        const float totA = __shfl(v0, 63);
        cden[bk * NCHUNK + t]      = v0 - a0;
        cden[bk * NCHUNK + 64 + t] = v1 - a1 + totA;
    }

    float run = 0.f;
    for (int g = 0; g < NCHUNK / 8; g++) {
        float vv[8];
#pragma unroll
        for (int j = 0; j < 8; j++)
            vv[j] = csum[((size_t)bk * NCHUNK + g * 8 + j) * 256 + pos];
#pragma unroll
        for (int j = 0; j < 8; j++) {
            const float x = vv[j];
            vv[j] = run;
            run += x;
        }
#pragma unroll
        for (int j = 0; j < 8; j++)
            csum[((size_t)bk * NCHUNK + g * 8 + j) * 256 + pos] = vv[j];
    }
}

// ---------------- phase 3: replay + epilogue (direct q, unroll 4) ------------
__global__ __launch_bounds__(256) void scan_out(const __bf16* __restrict__ q_b,
                                                const __bf16* __restrict__ k_val,
                                                const float* __restrict__ p_w,
                                                const float* __restrict__ theta,
                                                const float* __restrict__ csum,
                                                const float* __restrict__ cden,
                                                const float* __restrict__ W_re,
                                                const float* __restrict__ W_im,
                                                const float* __restrict__ norm_scale,
                                                __bf16* __restrict__ y) {
    const int idx = blockIdx.x;
    const int c = idx & (NCHUNK - 1);
    const int bkg = idx >> 7;
    const int kg = bkg & (KG_CNT - 1);
    const int b = bkg / KG_CNT;
    const int t = threadIdx.x;
    const int kl = t >> 5;
    const int h = t & 31;
    const int k = kg * 8 + kl;
    const int bk = b * K_TOT + k;

    const float A4 = theta[4];

    float r[4], im[4];
    {
        const float* base = &csum[((size_t)bk * NCHUNK + c) * 256 + h * 8];
        const f32x4 v0 = *(const f32x4*)base;
        const f32x4 v1 = *(const f32x4*)(base + 4);
        r[0] = v0.x; im[0] = v0.y; r[1] = v0.z; im[1] = v0.w;
        r[2] = v1.x; im[2] = v1.y; r[3] = v1.z; im[3] = v1.w;
    }
    float den = cden[bk * NCHUNK + c];

    const float wsc_re = norm_scale[h] * W_re[h * H_DIM + h];
    const float wsc_im = norm_scale[H_DIM + h] * W_im[h * H_DIM + h];

    const int l0 = c * CHUNK_L;
#pragma unroll 4
    for (int i = 0; i < CHUNK_L; i++) {
        const size_t bl = (size_t)b * L_SEQ + (l0 + i);
        const float p  = p_w[bl * K_TOT + k];
        const float kv = (float)k_val[bl * DIM_K + k * H_DIM + h];

        const __bf16* qp = &q_b[bl * DIM_Q + (size_t)(kg * H_DIM + h) * 16];
        const bf16x8 q0 = *(const bf16x8*)qp;
        const bf16x8 q1 = *(const bf16x8*)(qp + 8);

        float cc = __cosf(kv * A4), ss = __sinf(kv * A4);
        const float cd = fmaf(cc, cc, -(ss * ss));
        const float sd = 2.f * cc * ss;

        float ore = 0.f, oim = 0.f;
#pragma unroll
        for (int j = 0; j < 4; j++) {
            if (j > 0) {
                const float c2 = fmaf(cc, cd, -(ss * sd));
                ss = fmaf(ss, cd, cc * sd);
                cc = c2;
            }
            r[j]  = fmaf(p, cc, r[j]);
            im[j] = fmaf(p, ss, im[j]);
            const float qrm = (float)q1[2 * j];
            const float qim = (float)q1[2 * j + 1];
            const float qrj = (float)q0[2 * (3 - j)];
            const float qij = (float)q0[2 * (3 - j) + 1];
            ore = fmaf(r[j],  qrm + qrj, fmaf(im[j], qim - qij, ore));
            oim = fmaf(im[j], qrm - qrj, fmaf(-r[j], qim + qij, oim));
        }
        den += p;
        const float inv = __builtin_amdgcn_rcpf(fmaxf(den, 1e-4f));

        const float v = (ore * wsc_re + oim * wsc_im) * inv;
        const float yv = v * __builtin_amdgcn_rcpf(1.0f + __expf(-v));
        y[bl * DIM_K + k * H_DIM + h] = (__bf16)yv;
    }
}

// ---------------- launch ----------------
extern "C" void kernel_launch(void* const* d_in, const int* in_sizes, int n_in,
                              void* d_out, int out_size, void* d_ws, size_t ws_size,
                              hipStream_t stream) {
    const float* x            = (const float*)d_in[0];
    const float* W_in         = (const float*)d_in[1];
    const float* conv_k       = (const float*)d_in[2];
    const float* theta        = (const float*)d_in[3];
    const float* decay_slopes = (const float*)d_in[4];
    const float* anchor_slopes= (const float*)d_in[5];
    const float* score_scale  = (const float*)d_in[6];
    const float* W_re         = (const float*)d_in[7];
    const float* W_im         = (const float*)d_in[8];
    const float* norm_scale   = (const float*)d_in[9];
    const float* W_out        = (const float*)d_in[10];
    float* out = (float*)d_out;

    float* ws = (float*)d_ws;
    size_t off = 0;
    float* p_w    = ws + off; off += (size_t)BL_TOT * K_TOT;
    float* csum   = ws + off; off += (size_t)B_SZ * K_TOT * NCHUNK * 256;
    float* cden   = ws + off; off += (size_t)B_SZ * K_TOT * NCHUNK;
    __bf16* z_mem_b = (__bf16*)(ws + off); off += (size_t)BL_TOT * DIM_MEM / 2 + 8;
    __bf16* k_val   = (__bf16*)(ws + off); off += (size_t)BL_TOT * DIM_K / 2;
    __bf16* x_b     = (__bf16*)(ws + off); off += (size_t)BL_TOT * D_MODEL / 2;
    __bf16* W_in_T  = (__bf16*)(ws + off); off += (size_t)NPAD_IN * D_MODEL / 2;
    __bf16* W_out_T = (__bf16*)(ws + off); off += (size_t)D_MODEL * D_MODEL / 2;
    __bf16* y_b     = (__bf16*)(ws + off); off += (size_t)BL_TOT * DIM_K / 2;
    __bf16* q_b     = (__bf16*)(ws + off); off += (size_t)BL_TOT * DIM_Q / 2;

    // 0) merged prep
    prep_all<<<CAST_BLOCKS + TIN_BLOCKS + TOUT_BLOCKS, 256, 0, stream>>>(
        x, W_in, W_out, x_b, W_in_T, W_out_T);

    // 1) z = x @ W_in (128x256 single-buffered, row-major XCD mapping)
    gemm_big<<<(NPAD_IN / 256) * (BL_TOT / 128), 512, 0, stream>>>(
        x_b, W_in_T, z_mem_b, q_b, D_MODEL, NPAD_IN / 256);

    // 2) fused conv + per-chunk totals
    chunk_sums<<<B_SZ * KG_CNT * NCHUNK, 256, 0, stream>>>(
        z_mem_b, conv_k, score_scale, decay_slopes, anchor_slopes, theta,
        k_val, p_w, csum, cden);
    // 3) prefix (4x parallel) + replay
    chunk_prefix<<<B_SZ * K_TOT * 4, 64, 0, stream>>>(csum, cden);
    scan_out<<<B_SZ * KG_CNT * NCHUNK, 256, 0, stream>>>(q_b, k_val, p_w, theta, csum,
                                                         cden, W_re, W_im, norm_scale, y_b);
    // 4) out = y @ W_out (128^2, 8-wave pipelined)
    gemm_mid<<<(D_MODEL / 128) * (BL_TOT / 128), 512, 0, stream>>>(
        y_b, W_out_T, out, D_MODEL, D_MODEL, D_MODEL / 128);
}